// Round 5
// baseline (381.884 us; speedup 1.0000x reference)
//
#include <hip/hip_runtime.h>

#define HH 256       // hidden size
#define NB 64        // batch (segments)
#define ROWS 64      // rows per block tile
#define NTOT 262144  // NK == NC
#define THREADS 256  // 4 waves

typedef _Float16 half8 __attribute__((ext_vector_type(8)));
typedef _Float16 half4 __attribute__((ext_vector_type(4)));
typedef float f32x4 __attribute__((ext_vector_type(4)));

// act LDS tile: [row][k] fp16, 64 rows x 256 k = 32KB, row stride 512B.
// XOR swizzle: 2-way aliased (minimum possible for 16 rows over 32 banks),
// measured cost ~2.5% — acceptable.
__device__ __forceinline__ uint32_t swz(uint32_t r, uint32_t k) {
  return (((r << 9) + (k << 1)) ^ ((r & 7) << 4)) ^ ((r & 8) << 3);
}

// ---------------------------------------------------------------------------
// Heavy layer via MFMA, swapped operands:
//   D[m=j][n=r] = sum_k WT[j][k] * act[r][k]
// A-frag (weights): lane l -> WT[j0+jf*16+(l&15)][ks*32+(l>>4)*8 .. +8] (16B L2)
// B-frag (act):     lane l -> act[rf*16+(l&15)][ks*32+(l>>4)*8 .. +8]   (16B LDS)
// D-frag: r = l&15, j = (l>>4)*4 + reg -> 4 consecutive j per lane -> 8B write.
// Wave tile: 64r x 64j (j0 = wid*64) -> weight matrix read exactly once/block.
// MODE: 0 = relu; 1 = plain (trunk c); 2 = multiply seg_mean[segs[r]] (branch f)
// ---------------------------------------------------------------------------
template<int MODE>
__device__ __forceinline__ void heavy_layer(char* act, const _Float16* __restrict__ WT,
                                            const float* __restrict__ bias,
                                            const float* __restrict__ seg_mean,
                                            const int* segs, int tid)
{
  const int wid  = tid >> 6;
  const int lane = tid & 63;
  const int lr   = lane & 15;
  const int lg   = lane >> 4;
  const int j0   = wid << 6;

  f32x4 acc[4][4];  // [jf][rf]
#pragma unroll
  for (int jf = 0; jf < 4; ++jf)
#pragma unroll
    for (int rf = 0; rf < 4; ++rf)
      acc[jf][rf] = (f32x4){0.f, 0.f, 0.f, 0.f};

  const _Float16* wbase = WT + (j0 + lr) * HH + lg * 8;

#pragma unroll 2
  for (int ks = 0; ks < 8; ++ks) {
    half8 a[4];
#pragma unroll
    for (int jf = 0; jf < 4; ++jf)
      a[jf] = *(const half8*)(wbase + jf * 16 * HH + ks * 32);
    half8 b[4];
#pragma unroll
    for (int rf = 0; rf < 4; ++rf)
      b[rf] = *(const half8*)(act + swz(rf * 16 + lr, ks * 32 + lg * 8));
    __builtin_amdgcn_s_setprio(1);
#pragma unroll
    for (int jf = 0; jf < 4; ++jf)
#pragma unroll
      for (int rf = 0; rf < 4; ++rf)
        acc[jf][rf] = __builtin_amdgcn_mfma_f32_16x16x32_f16(a[jf], b[rf], acc[jf][rf], 0, 0, 0);
    __builtin_amdgcn_s_setprio(0);
  }

  __syncthreads();  // all waves done READING act before overwrite

#pragma unroll
  for (int jf = 0; jf < 4; ++jf) {
    f32x4 bj = *(const f32x4*)(bias + j0 + jf * 16 + lg * 4);
#pragma unroll
    for (int rf = 0; rf < 4; ++rf) {
      f32x4 v = acc[jf][rf] + bj;
      if (MODE == 2) {
        int s = segs[rf * 16 + lr];  // feat = f * seg_mean[seg[r]], fused
        f32x4 sm = *(const f32x4*)(seg_mean + s * HH + j0 + jf * 16 + lg * 4);
        v *= sm;
      }
      half4 h;
#pragma unroll
      for (int u = 0; u < 4; ++u) {
        float x = v[u];
        if (MODE == 0) x = fmaxf(x, 0.f);
        h[u] = (_Float16)x;
      }
      *(half4*)(act + swz(rf * 16 + lr, j0 + jf * 16 + lg * 4)) = h;
    }
  }
  __syncthreads();
}

// layer 1 via MFMA: F=3 -> H (relu), K padded 3 -> 32 with zeros.
// A[j][k] = W0[k][j] (k<3, else 0); B[k][r] = x[r][k] (k<3, else 0).
// 16 MFMAs per wave replace the former 64-iteration scalar loop.
__device__ __forceinline__ void layer1_mfma(char* act, const float* xs,
                                            const float* __restrict__ W0,
                                            const float* __restrict__ b0, int tid)
{
  const int wid  = tid >> 6;
  const int lane = tid & 63;
  const int lr   = lane & 15;
  const int lg   = lane >> 4;
  const int j0   = wid << 6;

  half8 a[4], b[4];
#pragma unroll
  for (int jf = 0; jf < 4; ++jf) {
    half8 v = {0, 0, 0, 0, 0, 0, 0, 0};
    if (lg == 0) {
      int j = j0 + jf * 16 + lr;
      v[0] = (_Float16)W0[j];
      v[1] = (_Float16)W0[HH + j];
      v[2] = (_Float16)W0[2 * HH + j];
    }
    a[jf] = v;
  }
#pragma unroll
  for (int rf = 0; rf < 4; ++rf) {
    half8 v = {0, 0, 0, 0, 0, 0, 0, 0};
    if (lg == 0) {
      int r = rf * 16 + lr;
      v[0] = (_Float16)xs[r * 3 + 0];
      v[1] = (_Float16)xs[r * 3 + 1];
      v[2] = (_Float16)xs[r * 3 + 2];
    }
    b[rf] = v;
  }

  f32x4 acc[4][4];
#pragma unroll
  for (int jf = 0; jf < 4; ++jf)
#pragma unroll
    for (int rf = 0; rf < 4; ++rf)
      acc[jf][rf] = (f32x4){0.f, 0.f, 0.f, 0.f};
  __builtin_amdgcn_s_setprio(1);
#pragma unroll
  for (int jf = 0; jf < 4; ++jf)
#pragma unroll
    for (int rf = 0; rf < 4; ++rf)
      acc[jf][rf] = __builtin_amdgcn_mfma_f32_16x16x32_f16(a[jf], b[rf], acc[jf][rf], 0, 0, 0);
  __builtin_amdgcn_s_setprio(0);

#pragma unroll
  for (int jf = 0; jf < 4; ++jf) {
    f32x4 bj = *(const f32x4*)(b0 + j0 + jf * 16 + lg * 4);
#pragma unroll
    for (int rf = 0; rf < 4; ++rf) {
      f32x4 v = acc[jf][rf] + bj;
      half4 h;
#pragma unroll
      for (int u = 0; u < 4; ++u)
        h[u] = (_Float16)fmaxf(v[u], 0.f);
      *(half4*)(act + swz(rf * 16 + lr, j0 + jf * 16 + lg * 4)) = h;
    }
  }
  __syncthreads();
}

// ---------------------------------------------------------------------------
__global__ __launch_bounds__(THREADS, 4)
void trunk_kernel(const float* __restrict__ nodes, const int* __restrict__ coord_seg,
                  const float* __restrict__ tw0, const float* __restrict__ tb0,
                  const _Float16* __restrict__ wt1, const float* __restrict__ tb1,
                  const _Float16* __restrict__ wt2, const float* __restrict__ tb2,
                  float* __restrict__ seg_sum)
{
  __shared__ __align__(16) char act[ROWS * HH * 2];  // 32KB
  __shared__ float xs[ROWS * 3];
  __shared__ int   segs[ROWS];
  const int tid = threadIdx.x;
  const int r0g = blockIdx.x * ROWS;

  if (tid < ROWS * 3) xs[tid] = nodes[r0g * 3 + tid];
  if (tid < ROWS) segs[tid] = coord_seg[r0g + tid];
  __syncthreads();

  layer1_mfma(act, xs, tw0, tb0, tid);
  heavy_layer<0>(act, wt1, tb1, nullptr, nullptr, tid);
  heavy_layer<1>(act, wt2, tb2, nullptr, nullptr, tid);  // c (no relu)

  // per-segment sums of c; segs sorted -> usually 1 distinct per 64-row tile.
  {
    const int j = tid;
    const int s_lo = segs[0], s_hi = segs[ROWS - 1];
    for (int s = s_lo; s <= s_hi; ++s) {
      float p = 0.f;
      for (int r = 0; r < ROWS; ++r)
        if (segs[r] == s)
          p += (float)*(const _Float16*)(act + swz(r, j));
      atomicAdd(&seg_sum[s * HH + j], p);
    }
  }
}

__global__ __launch_bounds__(THREADS, 4)
void branch_kernel(const float* __restrict__ known_nodes, const int* __restrict__ known_seg,
                   const float* __restrict__ bw0, const float* __restrict__ bb0,
                   const _Float16* __restrict__ wt1, const float* __restrict__ bb1,
                   const _Float16* __restrict__ wt2, const float* __restrict__ bb2,
                   const float* __restrict__ seg_mean,
                   const _Float16* __restrict__ wto, const float* __restrict__ ob0,
                   const float* __restrict__ ow1, const float* __restrict__ ob1,
                   float* __restrict__ out)
{
  __shared__ __align__(16) char act[ROWS * HH * 2];  // 32KB
  __shared__ float xs_ps[4 * ROWS * 3];              // xs (layer1) then partials
  __shared__ int   segs[ROWS];
  const int tid = threadIdx.x;
  const int r0g = blockIdx.x * ROWS;

  if (tid < ROWS * 3) xs_ps[tid] = known_nodes[r0g * 3 + tid];
  if (tid < ROWS) segs[tid] = known_seg[r0g + tid];
  __syncthreads();

  layer1_mfma(act, xs_ps, bw0, bb0, tid);
  heavy_layer<0>(act, wt1, bb1, nullptr, nullptr, tid);
  heavy_layer<2>(act, wt2, bb2, seg_mean, segs, tid);   // f * seg_mean (fused)
  heavy_layer<0>(act, wto, ob0, nullptr, nullptr, tid); // h = relu(feat@ow0+ob0)

  // out = h @ ow1 + ob1 (256 -> 3): all 256 threads, 4 k-quarters in parallel
  {
    const int r = tid & 63;
    const int q = tid >> 6;
    float o0 = 0.f, o1 = 0.f, o2 = 0.f;
    for (int kk = 0; kk < 64; kk += 8) {
      int k0 = q * 64 + kk;
      half8 h = *(const half8*)(act + swz(r, k0));
#pragma unroll
      for (int u = 0; u < 8; ++u) {
        float a = (float)h[u];
        o0 = fmaf(a, ow1[(k0 + u) * 3 + 0], o0);
        o1 = fmaf(a, ow1[(k0 + u) * 3 + 1], o1);
        o2 = fmaf(a, ow1[(k0 + u) * 3 + 2], o2);
      }
    }
    __syncthreads();  // xs_ps reuse
    float* ps = xs_ps + q * ROWS * 3;
    ps[r * 3 + 0] = o0; ps[r * 3 + 1] = o1; ps[r * 3 + 2] = o2;
  }
  __syncthreads();
  if (tid < ROWS) {
    const int r = tid;
    float* dst = out + (size_t)(r0g + r) * 3;
#pragma unroll
    for (int c = 0; c < 3; ++c) {
      float o = ob1[c];
#pragma unroll
      for (int q = 0; q < 4; ++q) o += xs_ps[q * ROWS * 3 + r * 3 + c];
      dst[c] = o;
    }
  }
}

// W[256][256] fp32 row-major -> WT[j][k] fp16 (5 matrices), once per launch.
struct WPtrs { const float* w[5]; _Float16* wt[5]; };
__global__ void transpose_kernel(WPtrs p)
{
  const int m = blockIdx.x >> 8;   // matrix
  const int j = blockIdx.x & 255;  // output row
  const int k = threadIdx.x;       // 256 threads, coalesced writes
  p.wt[m][j * HH + k] = (_Float16)p.w[m][k * HH + j];
}

__global__ void zero_kernel(float* __restrict__ p, int n)
{
  int i = blockIdx.x * blockDim.x + threadIdx.x;
  if (i < n) p[i] = 0.f;
}

__global__ void mean_kernel(const float* __restrict__ seg_sum,
                            const int* __restrict__ coord_seg,
                            float* __restrict__ seg_mean)
{
  const int b = blockIdx.x;
  int lo = 0, n = NTOT;
  while (n > 0) { int h = n >> 1; int mid = lo + h;
    if (coord_seg[mid] < b) { lo = mid + 1; n -= h + 1; } else n = h; }
  int hi = lo; n = NTOT - lo;
  while (n > 0) { int h = n >> 1; int mid = hi + h;
    if (coord_seg[mid] < b + 1) { hi = mid + 1; n -= h + 1; } else n = h; }
  float inv = 1.0f / fmaxf((float)(hi - lo), 1.0f);
  seg_mean[b * HH + threadIdx.x] = seg_sum[b * HH + threadIdx.x] * inv;
}

// ---------------------------------------------------------------------------
extern "C" void kernel_launch(void* const* d_in, const int* in_sizes, int n_in,
                              void* d_out, int out_size, void* d_ws, size_t ws_size,
                              hipStream_t stream)
{
  const float* known_nodes = (const float*)d_in[0];
  const float* nodes       = (const float*)d_in[1];
  const int*   known_seg   = (const int*)d_in[2];
  const int*   coord_seg   = (const int*)d_in[3];
  const float* bw0 = (const float*)d_in[4];
  const float* bb0 = (const float*)d_in[5];
  const float* bw1 = (const float*)d_in[6];
  const float* bb1 = (const float*)d_in[7];
  const float* bw2 = (const float*)d_in[8];
  const float* bb2 = (const float*)d_in[9];
  const float* tw0 = (const float*)d_in[10];
  const float* tb0 = (const float*)d_in[11];
  const float* tw1 = (const float*)d_in[12];
  const float* tb1 = (const float*)d_in[13];
  const float* tw2 = (const float*)d_in[14];
  const float* tb2 = (const float*)d_in[15];
  const float* ow0 = (const float*)d_in[16];
  const float* ob0 = (const float*)d_in[17];
  const float* ow1 = (const float*)d_in[18];
  const float* ob1 = (const float*)d_in[19];

  float* out      = (float*)d_out;
  float* seg_sum  = (float*)d_ws;                        // [64][256] f32
  float* seg_mean = seg_sum + NB * HH;                   // [64][256] f32
  _Float16* wtb   = (_Float16*)((char*)d_ws + (size_t)2 * NB * HH * 4);
  _Float16* wt_tw1 = wtb + 0 * HH * HH;
  _Float16* wt_tw2 = wtb + 1 * HH * HH;
  _Float16* wt_bw1 = wtb + 2 * HH * HH;
  _Float16* wt_bw2 = wtb + 3 * HH * HH;
  _Float16* wt_ow0 = wtb + 4 * HH * HH;

  WPtrs wp;
  wp.w[0] = tw1; wp.wt[0] = wt_tw1;
  wp.w[1] = tw2; wp.wt[1] = wt_tw2;
  wp.w[2] = bw1; wp.wt[2] = wt_bw1;
  wp.w[3] = bw2; wp.wt[3] = wt_bw2;
  wp.w[4] = ow0; wp.wt[4] = wt_ow0;

  transpose_kernel<<<5 * 256, 256, 0, stream>>>(wp);
  zero_kernel<<<(NB * HH + 255) / 256, 256, 0, stream>>>(seg_sum, NB * HH);
  trunk_kernel<<<NTOT / ROWS, THREADS, 0, stream>>>(nodes, coord_seg,
                                                    tw0, tb0, wt_tw1, tb1, wt_tw2, tb2,
                                                    seg_sum);
  mean_kernel<<<NB, 256, 0, stream>>>(seg_sum, coord_seg, seg_mean);
  branch_kernel<<<NTOT / ROWS, THREADS, 0, stream>>>(known_nodes, known_seg,
                                                     bw0, bb0, wt_bw1, bb1, wt_bw2, bb2,
                                                     seg_mean,
                                                     wt_ow0, ob0, ow1, ob1,
                                                     out);
}